// Round 20
// baseline (234.386 us; speedup 1.0000x reference)
//
#include <hip/hip_runtime.h>

#define NP 32
#define NROWS 65536
#define ATAB_N 4096               // intervals over [-6, 6]; h = 3/1024 exact
#define ATAB_H (3.0f / 1024.0f)
#define ATAB_SCALE (4096.0f / 12.0f)

typedef _Float16 f16x8 __attribute__((ext_vector_type(8)));
typedef _Float16 f16x4 __attribute__((ext_vector_type(4)));
typedef _Float16 f16x2 __attribute__((ext_vector_type(2)));
typedef float    f32x4 __attribute__((ext_vector_type(4)));

#define FAST_RCP(x) __builtin_amdgcn_rcpf(x)

__device__ __forceinline__ float fast_tanh(float v) {
    float e = __expf(2.0f * v);
    return fmaf(-2.0f, FAST_RCP(e + 1.0f), 1.0f);
}

__device__ __forceinline__ f16x4 pack4(float c0, float c1, float c2, float c3) {
    const f16x2 p01 = __builtin_bit_cast(f16x2, __builtin_amdgcn_cvt_pkrtz(c0, c1));
    const f16x2 p23 = __builtin_bit_cast(f16x2, __builtin_amdgcn_cvt_pkrtz(c2, c3));
    return __builtin_shufflevector(p01, p23, 0, 1, 2, 3);
}
__device__ __forceinline__ f16x8 cat8(f16x4 a, f16x4 b) {
    return __builtin_shufflevector(a, b, 0, 1, 2, 3, 4, 5, 6, 7);
}
__device__ __forceinline__ f16x4 tanh_pack(f32x4 a) {
    return pack4(fast_tanh(a[0]), fast_tanh(a[1]), fast_tanh(a[2]), fast_tanh(a[3]));
}
__device__ __forceinline__ f16x4 relu_pack(f32x4 a) {
    return pack4(fmaxf(a[0], 0.f), fmaxf(a[1], 0.f), fmaxf(a[2], 0.f), fmaxf(a[3], 0.f));
}
__device__ __forceinline__ f32x4 tanh4(f32x4 a) {
    return f32x4{fast_tanh(a[0]), fast_tanh(a[1]), fast_tanh(a[2]), fast_tanh(a[3])};
}

// ---- virtual-channel maps (verified r9-r19: absmax 0.0039) -----------------
__device__ __forceinline__ int col64(int k) {
    return 32 * (k >> 5) + 16 * ((k >> 2) & 1) + (((k >> 3) & 3) << 2) + (k & 3);
}
__device__ __forceinline__ int col32(int k) {
    return 16 * ((k >> 2) & 1) + ((k >> 3) << 2) + (k & 3);
}
__device__ __forceinline__ int col16(int k) {
    return (k & 3) | ((k >> 1) & 4) | ((k & 4) << 1);
}

// ---------------- prepacked weight storage (device globals) ----------------
// 17 MFMA steps (hi-only f16): B1:s0-3 (bias in k=31 col) B2:s4-7 B3:s8-9
// B4:s10  A2:s11-14 A3:s15 A4:s16. Main kernel uses s0-10; A-table builder
// uses s11-16. bias steps: B2:0-1 B3:2-3 B4:4 A2:5-6 A3:7 A4:8.
__device__ __align__(16) _Float16 g_frag[NP][17 * 64 * 8];
__device__ __align__(16) float    g_bias[NP][9 * 64 * 4];
__device__ __align__(16) float    g_a1w [NP][64 * 16];  // A1 in B-slot order
__device__ __align__(16) float    g_a1b [NP][64 * 16];
// fin: [0..15]=W56 (Wb6·Wb5), [16..31]=Wa5 zero-padded, [32]=b56, [33]=ba5
__device__ __align__(16) float    g_fin [NP][36];
// A-encoder tabulated: f_p at x = -6 + i*h, i = 0..4096
__device__ __align__(16) float    g_atab[NP][ATAB_N + 4];

// One block per (p, step) for the 17 frag steps + one per-p misc block.
__global__ void prep_frags(
    const float* __restrict__ Wa1, const float* __restrict__ ba1,
    const float* __restrict__ Wa2, const float* __restrict__ ba2,
    const float* __restrict__ Wa3, const float* __restrict__ ba3,
    const float* __restrict__ Wa4, const float* __restrict__ ba4,
    const float* __restrict__ Wa5, const float* __restrict__ ba5,
    const float* __restrict__ Wb1, const float* __restrict__ bb1,
    const float* __restrict__ Wb2, const float* __restrict__ bb2,
    const float* __restrict__ Wb3, const float* __restrict__ bb3,
    const float* __restrict__ Wb4, const float* __restrict__ bb4,
    const float* __restrict__ Wb5, const float* __restrict__ bb5,
    const float* __restrict__ Wb6, const float* __restrict__ bb6) {
    const int p    = blockIdx.x & 31;   // NP = 32
    const int task = blockIdx.x >> 5;   // 0..16 = frag step, 17 = misc
    const int l = threadIdx.x;          // 0..63
    const int g = l >> 4, q = l & 15;

    const int sw[17]  = {0,0,0,0, 1,1,1,1, 2,2, 3, 4,4,4,4, 5, 6};
    const int sMt[17] = {0,1,2,3, 0,0,1,1, 0,1, 0, 0,0,1,1, 0, 0};
    const int sks[17] = {0,0,0,0, 0,1,0,1, 0,0, 0, 0,1,0,1, 0, 0};
    const int OO[7] = {64,32,32,16,32,16, 8};
    const int II[7] = {31,64,32,32,64,32,16};
    const float* WS[7] = {Wb1 + p*1984, Wb2 + p*2048, Wb3 + p*1024,
                          Wb4 + p*512,  Wa2 + p*2048, Wa3 + p*512,
                          Wa4 + p*128};

    if (task < 17) {
        const int s = task;
        const int w = sw[s], O = OO[w], I = II[w];
        const float* W = WS[w];
        const float* b1s = bb1 + p*64;
#pragma unroll
        for (int e = 0; e < 8; ++e) {
            const int kk = 32*sks[s] + 8*g + e;   // layer-k slot
            const int o  = 16*sMt[s] + q;         // out (= A row)
            float wv = 0.0f;
            if (o < O) {
                if (s < 4) {        // B1: direct x order; col 31 = bias
                    wv = (kk < 31) ? W[o*31 + kk] : (kk == 31 ? b1s[o] : 0.0f);
                } else if (w == 1 || w == 4) {          // 64-wide input
                    wv = W[o*I + col64(kk)];
                } else if (w == 6) {                    // A4: 16-wide input
                    wv = (kk < 16) ? W[o*I + col16(kk)] : 0.0f;
                } else {                                // 32-wide input
                    wv = W[o*I + col32(kk)];
                }
            }
            g_frag[p][(s*64 + l)*8 + e] = (_Float16)wv;
        }
        return;
    }

    // ---- task 17: biases, A1 tables, fin ------------------------------------
    const int bw[9]  = {0,0, 1,1, 2, 3,3, 4, 5};
    const int bMt[9] = {0,1, 0,1, 0, 0,1, 0, 0};
    const float* BS[6] = {bb2 + p*32, bb3 + p*32, bb4 + p*16,
                          ba2 + p*32, ba3 + p*16, ba4 + p*8};
    const int BO[6] = {32,32,16,32,16,8};
#pragma unroll
    for (int bs = 0; bs < 9; ++bs) {
        const int w = bw[bs];
#pragma unroll
        for (int j = 0; j < 4; ++j) {
            const int o = 16*bMt[bs] + 4*g + j;
            g_bias[p][(bs*64 + l)*4 + j] = (o < BO[w]) ? BS[w][o] : 0.0f;
        }
    }
    // A1 weights directly in B-slot order (out channel = col64 of slot)
#pragma unroll
    for (int idx = 0; idx < 16; ++idx) {
        const int ks = idx >> 3, e = idx & 7;
        const int c = col64(32*ks + 8*g + e);
        g_a1w[p][l*16 + idx] = Wa1[p*64 + c];
        g_a1b[p][l*16 + idx] = ba1[p*64 + c];
    }
    // fin: W56 fold in parallel over 16 lanes, rest on lane 0
    if (l < 16) {
        float s = 0.0f;
        for (int o = 0; o < 8; ++o)
            s += Wb6[p*8 + o] * Wb5[p*128 + o*16 + l];
        g_fin[p][l] = s;
        g_fin[p][16 + l] = (l < 8) ? Wa5[p*8 + l] : 0.0f;
    }
    if (l == 0) {
        float s = bb6[p];
        for (int o = 0; o < 8; ++o) s += Wb6[p*8 + o] * bb5[p*8 + o];
        g_fin[p][32] = s;
        g_fin[p][33] = ba5[p];
    }
}

// ---------------- A-encoder table builder (unchanged from r16) --------------
#define ALOADN(s) nw = *(const f16x8*)(wla + ((s)*64 + l)*8);
#define AROT() cw = nw;
#define AMFMA(bop, acc) \
    acc = __builtin_amdgcn_mfma_f32_16x16x32_f16(cw, bop, acc, 0, 0, 0);

__global__ __launch_bounds__(256, 3) void build_atab(int dummy) {
    __shared__ __align__(16) _Float16 wla[6 * 64 * 8];   // steps 11..16, 6144 B
    const int p  = blockIdx.x / 17;
    const int rb = blockIdx.x % 17;
    const int wv = threadIdx.x >> 6;
    const int l  = threadIdx.x & 63;
    const int g  = l >> 4, q = l & 15;
    const int row0 = rb * 256 + wv * 64;

    {   // stage A-steps (bytes [11*1024, 17*1024) of g_frag[p])
        const uint4* src = (const uint4*)(&g_frag[p][11 * 512]);
        uint4* dst = (uint4*)wla;
        for (int i = threadIdx.x; i < 6144 / 16; i += 256) dst[i] = src[i];
    }
    const float* bias = g_bias[p];
    const float* fin  = g_fin[p];
    const f32x4 finA = *(const f32x4*)(fin + 16 + 4*g);
    const float ba5v = fin[33];
    const f32x4* a1wp = (const f32x4*)(g_a1w[p] + l*16);
    const f32x4* a1bp = (const f32x4*)(g_a1b[p] + l*16);
    f32x4 a1w[4], a1b[4];
#pragma unroll
    for (int i = 0; i < 4; ++i) { a1w[i] = a1wp[i]; a1b[i] = a1bp[i]; }

    float xa[4];
#pragma unroll
    for (int t = 0; t < 4; ++t)
        xa[t] = fmaf((float)(row0 + 16*t + q), ATAB_H, -6.0f);

    __syncthreads();

    f16x8 cw, nw;
    ALOADN(0);

    // A1: 1->64 relu on VALU
    f16x8 bA[4][2];
#pragma unroll
    for (int ks = 0; ks < 2; ++ks) {
#pragma unroll
        for (int t = 0; t < 4; ++t) {
            float c0[4], c1[4];
#pragma unroll
            for (int j = 0; j < 4; ++j) {
                c0[j] = fmaxf(fmaf(a1w[2*ks][j],   xa[t], a1b[2*ks][j]),   0.f);
                c1[j] = fmaxf(fmaf(a1w[2*ks+1][j], xa[t], a1b[2*ks+1][j]), 0.f);
            }
            bA[t][ks] = cat8(pack4(c0[0], c0[1], c0[2], c0[3]),
                             pack4(c1[0], c1[1], c1[2], c1[3]));
        }
    }

    // A2: 64->32 tanh (local steps 0-3, bias 5-6)
    f16x4 u[4][2];
#pragma unroll
    for (int Mt = 0; Mt < 2; ++Mt) {
        const f32x4 cb = *(const f32x4*)(bias + ((5 + Mt)*64 + l)*4);
        f32x4 a[4] = {cb, cb, cb, cb};
        AROT();
        ALOADN(1 + 2*Mt);
#pragma unroll
        for (int t = 0; t < 4; ++t) { AMFMA(bA[t][0], a[t]); }
        AROT();
        ALOADN(2 + 2*Mt);
#pragma unroll
        for (int t = 0; t < 4; ++t) { AMFMA(bA[t][1], a[t]); }
#pragma unroll
        for (int t = 0; t < 4; ++t) u[t][Mt] = tanh_pack(a[t]);
    }
    f16x8 a2[4];
#pragma unroll
    for (int t = 0; t < 4; ++t) a2[t] = cat8(u[t][0], u[t][1]);

    // A3: 32->16 tanh (local step 4, bias 7), halves swapped via xor32
    f16x8 a3f[4];
    {
        const f32x4 cb = *(const f32x4*)(bias + (7*64 + l)*4);
        AROT();
        ALOADN(5);
#pragma unroll
        for (int t = 0; t < 4; ++t) {
            f32x4 a = cb;
            AMFMA(a2[t], a);
            const f16x4 own = tanh_pack(a);
            const float2 ow = __builtin_bit_cast(float2, own);
            float2 pw;
            pw.x = __shfl_xor(ow.x, 32);
            pw.y = __shfl_xor(ow.y, 32);
            a3f[t] = cat8(own, __builtin_bit_cast(f16x4, pw));
        }
    }

    // A4: 16->8 tanh (local step 5, bias 8) + A5 dot + table store
    {
        const f32x4 cb = *(const f32x4*)(bias + (8*64 + l)*4);
        AROT();
#pragma unroll
        for (int t = 0; t < 4; ++t) {
            f32x4 a = cb;
            AMFMA(a3f[t], a);
            const f32x4 c = tanh4(a);
            float s = finA[0] * c[0];
            s = fmaf(finA[1], c[1], s);
            s = fmaf(finA[2], c[2], s);
            s = fmaf(finA[3], c[3], s);
            s += __shfl_xor(s, 16);
            s += __shfl_xor(s, 32);
            const int row = row0 + 16*t + q;
            if (g == 0 && row <= ATAB_N) g_atab[p][row] = s + ba5v;
        }
    }
}

// ---------------- main kernel: r19 body, launch_bounds(256,6) ---------------
// r19 counters: VALUBusy 58 + MfmaUtil 9.6 with Occupancy 38% -> ~1/3 of wall
// is uncovered latency at ~3 blocks/CU. LDS (11264) allows 14 blocks/CU; the
// cap was the (256,4) scheduling tier. (256,6) -> VGPR cap 85 (body needs
// ~80 incl. acc in the unified file) -> 6 blocks/CU, 75% occupancy cap.
#define LOADW(s) w = *(const f16x8*)(wlds + ((s)*64 + l)*8);
#define MFMAW(bop, acc) \
    acc = __builtin_amdgcn_mfma_f32_16x16x32_f16(w, bop, acc, 0, 0, 0);
#define BIAS4(bs) (*(const f32x4*)(bias + ((bs)*64 + l)*4))

__global__ __launch_bounds__(256, 6) void mlp_mfma(
    const float* __restrict__ x, float* __restrict__ out) {
    __shared__ __align__(16) _Float16 wlds[11 * 64 * 8];  // 11264 B

    const int L   = blockIdx.x;          // 0..4095
    const int xcd = L & 7;
    const int m   = L >> 3;
    const int p   = m & 31;              // feature
    const int rc  = xcd + 8 * (m >> 5);  // row chunk 0..127
    const int wv  = threadIdx.x >> 6;
    const int l   = threadIdx.x & 63;
    const int g   = l >> 4, q = l & 15;
    const int wrow = rc * 512 + wv * 128;   // 128 rows per wave

    {   // stage B-steps (11264 B) once per block
        const uint4* src = (const uint4*)(g_frag[p]);
        uint4* dst = (uint4*)wlds;
        for (int i = threadIdx.x; i < 11264 / 16; i += 256) dst[i] = src[i];
    }

    const float* bias = g_bias[p];
    const float* fin  = g_fin[p];
    const f32x4 finB = *(const f32x4*)(fin + 4*g);
    const float b56 = fin[32];

    __syncthreads();

#pragma unroll 1
    for (int hg = 0; hg < 2; ++hg) {
        const int row0 = wrow + hg * 64;

        // ---- x operands (vectorized) + A-table lerp -------------------------
        f16x8 bX[4];
        float av[4];
#pragma unroll
        for (int t = 0; t < 4; ++t) {
            const float* xr = x + (size_t)(row0 + 16*t + q) * NP;
            const f32x4 v0 = *(const f32x4*)(xr + 8*g);
            const f32x4 v1 = *(const f32x4*)(xr + 8*g + 4);
            const float ex = xr[(8*g + 8 < 32) ? (8*g + 8) : 31];
            float r[9] = {v0[0], v0[1], v0[2], v0[3],
                          v1[0], v1[1], v1[2], v1[3], ex};
            float c[8];
#pragma unroll
            for (int e = 0; e < 8; ++e) {
                const int k = 8*g + e;
                c[e] = (k < 31) ? ((k >= p) ? r[e + 1] : r[e]) : 1.0f;
            }
            bX[t] = cat8(pack4(c[0], c[1], c[2], c[3]),
                         pack4(c[4], c[5], c[6], c[7]));
            const float xa = xr[p];
            float u = (xa + 6.0f) * ATAB_SCALE;
            u = fminf(fmaxf(u, 0.0f), 4095.99f);
            const int i = (int)u;
            const float fr = u - (float)i;
            const float t0 = g_atab[p][i];
            const float t1 = g_atab[p][i + 1];
            av[t] = fmaf(fr, t1 - t0, t0);
        }

        f16x8 w;

        // ---- B1: 31->64 relu (bias folded in k=31 column), steps 0-3 -------
        f16x4 h[4][4];
#pragma unroll
        for (int Mt = 0; Mt < 4; ++Mt) {
            LOADW(Mt);
#pragma unroll
            for (int t = 0; t < 4; ++t) {
                f32x4 a{0.f, 0.f, 0.f, 0.f};
                MFMAW(bX[t], a);
                h[t][Mt] = relu_pack(a);
            }
        }
        f16x8 bk[4][2];
#pragma unroll
        for (int t = 0; t < 4; ++t) {
            bk[t][0] = cat8(h[t][0], h[t][1]);
            bk[t][1] = cat8(h[t][2], h[t][3]);
        }

        // ---- B2: 64->32 tanh (steps 4-7, bias 0-1) -------------------------
        f16x4 u[4][2];
#pragma unroll
        for (int Mt = 0; Mt < 2; ++Mt) {
            const f32x4 cb = BIAS4(0 + Mt);
            f16x8 w0 = *(const f16x8*)(wlds + ((4 + 2*Mt)*64 + l)*8);
            f16x8 w1 = *(const f16x8*)(wlds + ((5 + 2*Mt)*64 + l)*8);
#pragma unroll
            for (int t = 0; t < 4; ++t) {
                f32x4 a = cb;
                a = __builtin_amdgcn_mfma_f32_16x16x32_f16(w0, bk[t][0], a, 0, 0, 0);
                a = __builtin_amdgcn_mfma_f32_16x16x32_f16(w1, bk[t][1], a, 0, 0, 0);
                u[t][Mt] = tanh_pack(a);
            }
        }
        f16x8 b2[4];
#pragma unroll
        for (int t = 0; t < 4; ++t) b2[t] = cat8(u[t][0], u[t][1]);

        // ---- B3: 32->32 tanh (steps 8-9, bias 2-3) -------------------------
#pragma unroll
        for (int Mt = 0; Mt < 2; ++Mt) {
            const f32x4 cb = BIAS4(2 + Mt);
            LOADW(8 + Mt);
#pragma unroll
            for (int t = 0; t < 4; ++t) {
                f32x4 a = cb;
                MFMAW(b2[t], a);
                u[t][Mt] = tanh_pack(a);
            }
        }
        f16x8 b3[4];
#pragma unroll
        for (int t = 0; t < 4; ++t) b3[t] = cat8(u[t][0], u[t][1]);

        // ---- B4: 32->16 tanh (step 10, bias 4) + folded B5·B6 dot + store --
        {
            const f32x4 cb = BIAS4(4);
            LOADW(10);
#pragma unroll
            for (int t = 0; t < 4; ++t) {
                f32x4 a = cb;
                MFMAW(b3[t], a);
                const f32x4 c = tanh4(a);
                float s = finB[0] * c[0];
                s = fmaf(finB[1], c[1], s);
                s = fmaf(finB[2], c[2], s);
                s = fmaf(finB[3], c[3], s);
                s += __shfl_xor(s, 16);
                s += __shfl_xor(s, 32);
                const float bv = s + b56;
                if (g == 0) {
                    const int grow = row0 + 16*t + q;
                    reinterpret_cast<float2*>(out)[(size_t)grow * NP + p] =
                        make_float2(av[t], bv);
                }
            }
        }
    }
}

extern "C" void kernel_launch(void* const* d_in, const int* in_sizes, int n_in,
                              void* d_out, int out_size, void* d_ws,
                              size_t ws_size, hipStream_t stream) {
    const float* x   = (const float*)d_in[0];
    const float* Wa1 = (const float*)d_in[1];
    const float* ba1 = (const float*)d_in[2];
    const float* Wa2 = (const float*)d_in[3];
    const float* ba2 = (const float*)d_in[4];
    const float* Wa3 = (const float*)d_in[5];
    const float* ba3 = (const float*)d_in[6];
    const float* Wa4 = (const float*)d_in[7];
    const float* ba4 = (const float*)d_in[8];
    const float* Wa5 = (const float*)d_in[9];
    const float* ba5 = (const float*)d_in[10];
    const float* Wb1 = (const float*)d_in[11];
    const float* bb1 = (const float*)d_in[12];
    const float* Wb2 = (const float*)d_in[13];
    const float* bb2 = (const float*)d_in[14];
    const float* Wb3 = (const float*)d_in[15];
    const float* bb3 = (const float*)d_in[16];
    const float* Wb4 = (const float*)d_in[17];
    const float* bb4 = (const float*)d_in[18];
    const float* Wb5 = (const float*)d_in[19];
    const float* bb5 = (const float*)d_in[20];
    const float* Wb6 = (const float*)d_in[21];
    const float* bb6 = (const float*)d_in[22];

    prep_frags<<<dim3(NP * 18), dim3(64), 0, stream>>>(
        Wa1, ba1, Wa2, ba2, Wa3, ba3, Wa4, ba4, Wa5, ba5,
        Wb1, bb1, Wb2, bb2, Wb3, bb3, Wb4, bb4, Wb5, bb5, Wb6, bb6);

    build_atab<<<dim3(NP * 17), dim3(256), 0, stream>>>(0);

    mlp_mfma<<<dim3(NROWS / 512 * NP), 256, 0, stream>>>(x, (float*)d_out);
}

// Round 21
// 146.705 us; speedup vs baseline: 1.5977x; 1.5977x over previous
//
#include <hip/hip_runtime.h>

#define NP 32
#define NROWS 65536
#define ATAB_N 4096               // intervals over [-6, 6]; h = 3/1024 exact
#define ATAB_H (3.0f / 1024.0f)
#define ATAB_SCALE (4096.0f / 12.0f)

typedef _Float16 f16x8 __attribute__((ext_vector_type(8)));
typedef _Float16 f16x4 __attribute__((ext_vector_type(4)));
typedef _Float16 f16x2 __attribute__((ext_vector_type(2)));
typedef float    f32x4 __attribute__((ext_vector_type(4)));

#define FAST_RCP(x) __builtin_amdgcn_rcpf(x)

__device__ __forceinline__ float fast_tanh(float v) {
    float e = __expf(2.0f * v);
    return fmaf(-2.0f, FAST_RCP(e + 1.0f), 1.0f);
}

__device__ __forceinline__ f16x4 pack4(float c0, float c1, float c2, float c3) {
    const f16x2 p01 = __builtin_bit_cast(f16x2, __builtin_amdgcn_cvt_pkrtz(c0, c1));
    const f16x2 p23 = __builtin_bit_cast(f16x2, __builtin_amdgcn_cvt_pkrtz(c2, c3));
    return __builtin_shufflevector(p01, p23, 0, 1, 2, 3);
}
__device__ __forceinline__ f16x8 cat8(f16x4 a, f16x4 b) {
    return __builtin_shufflevector(a, b, 0, 1, 2, 3, 4, 5, 6, 7);
}
__device__ __forceinline__ f16x4 tanh_pack(f32x4 a) {
    return pack4(fast_tanh(a[0]), fast_tanh(a[1]), fast_tanh(a[2]), fast_tanh(a[3]));
}
// relu on packed f16 (v_pk_max_f16 x2) where available; else f32 path.
__device__ __forceinline__ f16x4 relu_pack(f32x4 a) {
#if __has_builtin(__builtin_elementwise_max)
    f16x4 v = pack4(a[0], a[1], a[2], a[3]);
    const f16x4 z = {(_Float16)0, (_Float16)0, (_Float16)0, (_Float16)0};
    return __builtin_elementwise_max(v, z);
#else
    return pack4(fmaxf(a[0], 0.f), fmaxf(a[1], 0.f), fmaxf(a[2], 0.f),
                 fmaxf(a[3], 0.f));
#endif
}
__device__ __forceinline__ f32x4 tanh4(f32x4 a) {
    return f32x4{fast_tanh(a[0]), fast_tanh(a[1]), fast_tanh(a[2]), fast_tanh(a[3])};
}

// ---- virtual-channel maps (verified r9-r19: absmax 0.0039) -----------------
__device__ __forceinline__ int col64(int k) {
    return 32 * (k >> 5) + 16 * ((k >> 2) & 1) + (((k >> 3) & 3) << 2) + (k & 3);
}
__device__ __forceinline__ int col32(int k) {
    return 16 * ((k >> 2) & 1) + ((k >> 3) << 2) + (k & 3);
}
__device__ __forceinline__ int col16(int k) {
    return (k & 3) | ((k >> 1) & 4) | ((k & 4) << 1);
}

// ---------------- prepacked weight storage (device globals) ----------------
// 17 MFMA steps (hi-only f16): B1:s0-3 (FULL 32-wide x input; col p zeroed,
// bias via f32 acc-init) B2:s4-7 B3:s8-9 B4:s10  A2:s11-14 A3:s15 A4:s16.
// bias steps: B2:0-1 B3:2-3 B4:4 A2:5-6 A3:7 A4:8 B1:9-12.
__device__ __align__(16) _Float16 g_frag[NP][17 * 64 * 8];
__device__ __align__(16) float    g_bias[NP][13 * 64 * 4];
__device__ __align__(16) float    g_a1w [NP][64 * 16];  // A1 in B-slot order
__device__ __align__(16) float    g_a1b [NP][64 * 16];
// fin: [0..15]=W56 (Wb6·Wb5), [16..31]=Wa5 zero-padded, [32]=b56, [33]=ba5
__device__ __align__(16) float    g_fin [NP][36];
// A-encoder tabulated: f_p at x = -6 + i*h, i = 0..4096
__device__ __align__(16) float    g_atab[NP][ATAB_N + 4];

// One block per (p, step) for the 17 frag steps + one per-p misc block.
__global__ void prep_frags(
    const float* __restrict__ Wa1, const float* __restrict__ ba1,
    const float* __restrict__ Wa2, const float* __restrict__ ba2,
    const float* __restrict__ Wa3, const float* __restrict__ ba3,
    const float* __restrict__ Wa4, const float* __restrict__ ba4,
    const float* __restrict__ Wa5, const float* __restrict__ ba5,
    const float* __restrict__ Wb1, const float* __restrict__ bb1,
    const float* __restrict__ Wb2, const float* __restrict__ bb2,
    const float* __restrict__ Wb3, const float* __restrict__ bb3,
    const float* __restrict__ Wb4, const float* __restrict__ bb4,
    const float* __restrict__ Wb5, const float* __restrict__ bb5,
    const float* __restrict__ Wb6, const float* __restrict__ bb6) {
    const int p    = blockIdx.x & 31;   // NP = 32
    const int task = blockIdx.x >> 5;   // 0..16 = frag step, 17 = misc
    const int l = threadIdx.x;          // 0..63
    const int g = l >> 4, q = l & 15;

    const int sw[17]  = {0,0,0,0, 1,1,1,1, 2,2, 3, 4,4,4,4, 5, 6};
    const int sMt[17] = {0,1,2,3, 0,0,1,1, 0,1, 0, 0,0,1,1, 0, 0};
    const int sks[17] = {0,0,0,0, 0,1,0,1, 0,0, 0, 0,1,0,1, 0, 0};
    const int OO[7] = {64,32,32,16,32,16, 8};
    const int II[7] = {31,64,32,32,64,32,16};
    const float* WS[7] = {Wb1 + p*1984, Wb2 + p*2048, Wb3 + p*1024,
                          Wb4 + p*512,  Wa2 + p*2048, Wa3 + p*512,
                          Wa4 + p*128};

    if (task < 17) {
        const int s = task;
        const int w = sw[s], O = OO[w], I = II[w];
        const float* W = WS[w];
#pragma unroll
        for (int e = 0; e < 8; ++e) {
            const int kk = 32*sks[s] + 8*g + e;   // layer-k slot
            const int o  = 16*sMt[s] + q;         // out (= A row)
            float wv = 0.0f;
            if (o < O) {
                if (s < 4) {        // B1: full 32-wide x; col p zeroed
                    wv = (kk == p) ? 0.0f : W[o*31 + kk - (kk > p ? 1 : 0)];
                } else if (w == 1 || w == 4) {          // 64-wide input
                    wv = W[o*I + col64(kk)];
                } else if (w == 6) {                    // A4: 16-wide input
                    wv = (kk < 16) ? W[o*I + col16(kk)] : 0.0f;
                } else {                                // 32-wide input
                    wv = W[o*I + col32(kk)];
                }
            }
            g_frag[p][(s*64 + l)*8 + e] = (_Float16)wv;
        }
        return;
    }

    // ---- task 17: biases, A1 tables, fin ------------------------------------
    // bias steps: 0-8 as before; 9-12 = B1 bias (64-wide, Mt 0..3)
    const int bw[13]  = {0,0, 1,1, 2, 3,3, 4, 5, 6,6,6,6};
    const int bMt[13] = {0,1, 0,1, 0, 0,1, 0, 0, 0,1,2,3};
    const float* BS[7] = {bb2 + p*32, bb3 + p*32, bb4 + p*16,
                          ba2 + p*32, ba3 + p*16, ba4 + p*8, bb1 + p*64};
    const int BO[7] = {32,32,16,32,16,8,64};
#pragma unroll
    for (int bs = 0; bs < 13; ++bs) {
        const int w = bw[bs];
#pragma unroll
        for (int j = 0; j < 4; ++j) {
            const int o = 16*bMt[bs] + 4*g + j;
            g_bias[p][(bs*64 + l)*4 + j] = (o < BO[w]) ? BS[w][o] : 0.0f;
        }
    }
    // A1 weights directly in B-slot order (out channel = col64 of slot)
#pragma unroll
    for (int idx = 0; idx < 16; ++idx) {
        const int ks = idx >> 3, e = idx & 7;
        const int c = col64(32*ks + 8*g + e);
        g_a1w[p][l*16 + idx] = Wa1[p*64 + c];
        g_a1b[p][l*16 + idx] = ba1[p*64 + c];
    }
    // fin: W56 fold in parallel over 16 lanes, rest on lane 0
    if (l < 16) {
        float s = 0.0f;
        for (int o = 0; o < 8; ++o)
            s += Wb6[p*8 + o] * Wb5[p*128 + o*16 + l];
        g_fin[p][l] = s;
        g_fin[p][16 + l] = (l < 8) ? Wa5[p*8 + l] : 0.0f;
    }
    if (l == 0) {
        float s = bb6[p];
        for (int o = 0; o < 8; ++o) s += Wb6[p*8 + o] * bb5[p*8 + o];
        g_fin[p][32] = s;
        g_fin[p][33] = ba5[p];
    }
}

// ---------------- A-encoder table builder (unchanged) -----------------------
#define ALOADN(s) nw = *(const f16x8*)(wla + ((s)*64 + l)*8);
#define AROT() cw = nw;
#define AMFMA(bop, acc) \
    acc = __builtin_amdgcn_mfma_f32_16x16x32_f16(cw, bop, acc, 0, 0, 0);

__global__ __launch_bounds__(256, 3) void build_atab(int dummy) {
    __shared__ __align__(16) _Float16 wla[6 * 64 * 8];   // steps 11..16, 6144 B
    const int p  = blockIdx.x / 17;
    const int rb = blockIdx.x % 17;
    const int wv = threadIdx.x >> 6;
    const int l  = threadIdx.x & 63;
    const int g  = l >> 4, q = l & 15;
    const int row0 = rb * 256 + wv * 64;

    {   // stage A-steps (bytes [11*1024, 17*1024) of g_frag[p])
        const uint4* src = (const uint4*)(&g_frag[p][11 * 512]);
        uint4* dst = (uint4*)wla;
        for (int i = threadIdx.x; i < 6144 / 16; i += 256) dst[i] = src[i];
    }
    const float* bias = g_bias[p];
    const float* fin  = g_fin[p];
    const f32x4 finA = *(const f32x4*)(fin + 16 + 4*g);
    const float ba5v = fin[33];
    const f32x4* a1wp = (const f32x4*)(g_a1w[p] + l*16);
    const f32x4* a1bp = (const f32x4*)(g_a1b[p] + l*16);
    f32x4 a1w[4], a1b[4];
#pragma unroll
    for (int i = 0; i < 4; ++i) { a1w[i] = a1wp[i]; a1b[i] = a1bp[i]; }

    float xa[4];
#pragma unroll
    for (int t = 0; t < 4; ++t)
        xa[t] = fmaf((float)(row0 + 16*t + q), ATAB_H, -6.0f);

    __syncthreads();

    f16x8 cw, nw;
    ALOADN(0);

    // A1: 1->64 relu on VALU
    f16x8 bA[4][2];
#pragma unroll
    for (int ks = 0; ks < 2; ++ks) {
#pragma unroll
        for (int t = 0; t < 4; ++t) {
            float c0[4], c1[4];
#pragma unroll
            for (int j = 0; j < 4; ++j) {
                c0[j] = fmaxf(fmaf(a1w[2*ks][j],   xa[t], a1b[2*ks][j]),   0.f);
                c1[j] = fmaxf(fmaf(a1w[2*ks+1][j], xa[t], a1b[2*ks+1][j]), 0.f);
            }
            bA[t][ks] = cat8(pack4(c0[0], c0[1], c0[2], c0[3]),
                             pack4(c1[0], c1[1], c1[2], c1[3]));
        }
    }

    // A2: 64->32 tanh (local steps 0-3, bias 5-6)
    f16x4 u[4][2];
#pragma unroll
    for (int Mt = 0; Mt < 2; ++Mt) {
        const f32x4 cb = *(const f32x4*)(bias + ((5 + Mt)*64 + l)*4);
        f32x4 a[4] = {cb, cb, cb, cb};
        AROT();
        ALOADN(1 + 2*Mt);
#pragma unroll
        for (int t = 0; t < 4; ++t) { AMFMA(bA[t][0], a[t]); }
        AROT();
        ALOADN(2 + 2*Mt);
#pragma unroll
        for (int t = 0; t < 4; ++t) { AMFMA(bA[t][1], a[t]); }
#pragma unroll
        for (int t = 0; t < 4; ++t) u[t][Mt] = tanh_pack(a[t]);
    }
    f16x8 a2[4];
#pragma unroll
    for (int t = 0; t < 4; ++t) a2[t] = cat8(u[t][0], u[t][1]);

    // A3: 32->16 tanh (local step 4, bias 7), halves swapped via xor32
    f16x8 a3f[4];
    {
        const f32x4 cb = *(const f32x4*)(bias + (7*64 + l)*4);
        AROT();
        ALOADN(5);
#pragma unroll
        for (int t = 0; t < 4; ++t) {
            f32x4 a = cb;
            AMFMA(a2[t], a);
            const f16x4 own = tanh_pack(a);
            const float2 ow = __builtin_bit_cast(float2, own);
            float2 pw;
            pw.x = __shfl_xor(ow.x, 32);
            pw.y = __shfl_xor(ow.y, 32);
            a3f[t] = cat8(own, __builtin_bit_cast(f16x4, pw));
        }
    }

    // A4: 16->8 tanh (local step 5, bias 8) + A5 dot + table store
    {
        const f32x4 cb = *(const f32x4*)(bias + (8*64 + l)*4);
        AROT();
#pragma unroll
        for (int t = 0; t < 4; ++t) {
            f32x4 a = cb;
            AMFMA(a3f[t], a);
            const f32x4 c = tanh4(a);
            float s = finA[0] * c[0];
            s = fmaf(finA[1], c[1], s);
            s = fmaf(finA[2], c[2], s);
            s = fmaf(finA[3], c[3], s);
            s += __shfl_xor(s, 16);
            s += __shfl_xor(s, 32);
            const int row = row0 + 16*t + q;
            if (g == 0 && row <= ATAB_N) g_atab[p][row] = s + ba5v;
        }
    }
}

// ---------------- main kernel: r19 body + direct-x B1 + pk relu -------------
// (256,4) is the occupancy ceiling: unified-file AGPR block (~44) + arch 64
// fits the 128 budget; 6-wave tier leaves 85-44=40 arch -> spills (r14/r20).
#define LOADW(s) w = *(const f16x8*)(wlds + ((s)*64 + l)*8);
#define MFMAW(bop, acc) \
    acc = __builtin_amdgcn_mfma_f32_16x16x32_f16(w, bop, acc, 0, 0, 0);
#define BIAS4(bs) (*(const f32x4*)(bias + ((bs)*64 + l)*4))

__global__ __launch_bounds__(256, 4) void mlp_mfma(
    const float* __restrict__ x, float* __restrict__ out) {
    __shared__ __align__(16) _Float16 wlds[11 * 64 * 8];  // 11264 B

    const int L   = blockIdx.x;          // 0..4095
    const int xcd = L & 7;
    const int m   = L >> 3;
    const int p   = m & 31;              // feature
    const int rc  = xcd + 8 * (m >> 5);  // row chunk 0..127
    const int wv  = threadIdx.x >> 6;
    const int l   = threadIdx.x & 63;
    const int g   = l >> 4, q = l & 15;
    const int wrow = rc * 512 + wv * 128;   // 128 rows per wave

    {   // stage B-steps (11264 B) once per block
        const uint4* src = (const uint4*)(g_frag[p]);
        uint4* dst = (uint4*)wlds;
        for (int i = threadIdx.x; i < 11264 / 16; i += 256) dst[i] = src[i];
    }

    const float* bias = g_bias[p];
    const float* fin  = g_fin[p];
    const f32x4 finB = *(const f32x4*)(fin + 4*g);
    const float b56 = fin[32];

    __syncthreads();

#pragma unroll 1
    for (int hg = 0; hg < 2; ++hg) {
        const int row0 = wrow + hg * 64;

        // ---- x operands: direct f32->f16 pack (no leave-one-out selects) ----
        f16x8 bX[4];
        float av[4];
#pragma unroll
        for (int t = 0; t < 4; ++t) {
            const float* xr = x + (size_t)(row0 + 16*t + q) * NP;
            const f32x4 v0 = *(const f32x4*)(xr + 8*g);
            const f32x4 v1 = *(const f32x4*)(xr + 8*g + 4);
            bX[t] = cat8(pack4(v0[0], v0[1], v0[2], v0[3]),
                         pack4(v1[0], v1[1], v1[2], v1[3]));
            const float xa = xr[p];
            float u = (xa + 6.0f) * ATAB_SCALE;
            u = fminf(fmaxf(u, 0.0f), 4095.99f);
            const int i = (int)u;
            const float fr = u - (float)i;
            const float t0 = g_atab[p][i];
            const float t1 = g_atab[p][i + 1];
            av[t] = fmaf(fr, t1 - t0, t0);
        }

        f16x8 w;

        // ---- B1: 32-wide x -> 64 relu (col p zeroed; f32 bias init 9-12) ---
        f16x4 h[4][4];
#pragma unroll
        for (int Mt = 0; Mt < 4; ++Mt) {
            const f32x4 cb = BIAS4(9 + Mt);
            LOADW(Mt);
#pragma unroll
            for (int t = 0; t < 4; ++t) {
                f32x4 a = cb;
                MFMAW(bX[t], a);
                h[t][Mt] = relu_pack(a);
            }
        }
        f16x8 bk[4][2];
#pragma unroll
        for (int t = 0; t < 4; ++t) {
            bk[t][0] = cat8(h[t][0], h[t][1]);
            bk[t][1] = cat8(h[t][2], h[t][3]);
        }

        // ---- B2: 64->32 tanh (steps 4-7, bias 0-1) -------------------------
        f16x4 u[4][2];
#pragma unroll
        for (int Mt = 0; Mt < 2; ++Mt) {
            const f32x4 cb = BIAS4(0 + Mt);
            f16x8 w0 = *(const f16x8*)(wlds + ((4 + 2*Mt)*64 + l)*8);
            f16x8 w1 = *(const f16x8*)(wlds + ((5 + 2*Mt)*64 + l)*8);
#pragma unroll
            for (int t = 0; t < 4; ++t) {
                f32x4 a = cb;
                a = __builtin_amdgcn_mfma_f32_16x16x32_f16(w0, bk[t][0], a, 0, 0, 0);
                a = __builtin_amdgcn_mfma_f32_16x16x32_f16(w1, bk[t][1], a, 0, 0, 0);
                u[t][Mt] = tanh_pack(a);
            }
        }
        f16x8 b2[4];
#pragma unroll
        for (int t = 0; t < 4; ++t) b2[t] = cat8(u[t][0], u[t][1]);

        // ---- B3: 32->32 tanh (steps 8-9, bias 2-3) -------------------------
#pragma unroll
        for (int Mt = 0; Mt < 2; ++Mt) {
            const f32x4 cb = BIAS4(2 + Mt);
            LOADW(8 + Mt);
#pragma unroll
            for (int t = 0; t < 4; ++t) {
                f32x4 a = cb;
                MFMAW(b2[t], a);
                u[t][Mt] = tanh_pack(a);
            }
        }
        f16x8 b3[4];
#pragma unroll
        for (int t = 0; t < 4; ++t) b3[t] = cat8(u[t][0], u[t][1]);

        // ---- B4: 32->16 tanh (step 10, bias 4) + folded B5·B6 dot + store --
        {
            const f32x4 cb = BIAS4(4);
            LOADW(10);
#pragma unroll
            for (int t = 0; t < 4; ++t) {
                f32x4 a = cb;
                MFMAW(b3[t], a);
                const f32x4 c = tanh4(a);
                float s = finB[0] * c[0];
                s = fmaf(finB[1], c[1], s);
                s = fmaf(finB[2], c[2], s);
                s = fmaf(finB[3], c[3], s);
                s += __shfl_xor(s, 16);
                s += __shfl_xor(s, 32);
                const float bv = s + b56;
                if (g == 0) {
                    const int grow = row0 + 16*t + q;
                    reinterpret_cast<float2*>(out)[(size_t)grow * NP + p] =
                        make_float2(av[t], bv);
                }
            }
        }
    }
}

extern "C" void kernel_launch(void* const* d_in, const int* in_sizes, int n_in,
                              void* d_out, int out_size, void* d_ws,
                              size_t ws_size, hipStream_t stream) {
    const float* x   = (const float*)d_in[0];
    const float* Wa1 = (const float*)d_in[1];
    const float* ba1 = (const float*)d_in[2];
    const float* Wa2 = (const float*)d_in[3];
    const float* ba2 = (const float*)d_in[4];
    const float* Wa3 = (const float*)d_in[5];
    const float* ba3 = (const float*)d_in[6];
    const float* Wa4 = (const float*)d_in[7];
    const float* ba4 = (const float*)d_in[8];
    const float* Wa5 = (const float*)d_in[9];
    const float* ba5 = (const float*)d_in[10];
    const float* Wb1 = (const float*)d_in[11];
    const float* bb1 = (const float*)d_in[12];
    const float* Wb2 = (const float*)d_in[13];
    const float* bb2 = (const float*)d_in[14];
    const float* Wb3 = (const float*)d_in[15];
    const float* bb3 = (const float*)d_in[16];
    const float* Wb4 = (const float*)d_in[17];
    const float* bb4 = (const float*)d_in[18];
    const float* Wb5 = (const float*)d_in[19];
    const float* bb5 = (const float*)d_in[20];
    const float* Wb6 = (const float*)d_in[21];
    const float* bb6 = (const float*)d_in[22];

    prep_frags<<<dim3(NP * 18), dim3(64), 0, stream>>>(
        Wa1, ba1, Wa2, ba2, Wa3, ba3, Wa4, ba4, Wa5, ba5,
        Wb1, bb1, Wb2, bb2, Wb3, bb3, Wb4, bb4, Wb5, bb5, Wb6, bb6);

    build_atab<<<dim3(NP * 17), dim3(256), 0, stream>>>(0);

    mlp_mfma<<<dim3(NROWS / 512 * NP), 256, 0, stream>>>(x, (float*)d_out);
}

// Round 22
// 123.423 us; speedup vs baseline: 1.8990x; 1.1886x over previous
//
#include <hip/hip_runtime.h>

#define NP 32
#define NROWS 65536
#define ATAB_N 4096               // intervals over [-6, 6]; h = 3/1024 exact
#define ATAB_H (3.0f / 1024.0f)
#define ATAB_SCALE (4096.0f / 12.0f)

typedef _Float16 f16x8 __attribute__((ext_vector_type(8)));
typedef _Float16 f16x4 __attribute__((ext_vector_type(4)));
typedef _Float16 f16x2 __attribute__((ext_vector_type(2)));
typedef float    f32x4 __attribute__((ext_vector_type(4)));

#define FAST_RCP(x) __builtin_amdgcn_rcpf(x)

__device__ __forceinline__ float fast_tanh(float v) {
    float e = __expf(2.0f * v);
    return fmaf(-2.0f, FAST_RCP(e + 1.0f), 1.0f);
}

__device__ __forceinline__ f16x4 pack4(float c0, float c1, float c2, float c3) {
    const f16x2 p01 = __builtin_bit_cast(f16x2, __builtin_amdgcn_cvt_pkrtz(c0, c1));
    const f16x2 p23 = __builtin_bit_cast(f16x2, __builtin_amdgcn_cvt_pkrtz(c2, c3));
    return __builtin_shufflevector(p01, p23, 0, 1, 2, 3);
}
__device__ __forceinline__ f16x8 cat8(f16x4 a, f16x4 b) {
    return __builtin_shufflevector(a, b, 0, 1, 2, 3, 4, 5, 6, 7);
}
__device__ __forceinline__ f16x4 tanh_pack(f32x4 a) {
    return pack4(fast_tanh(a[0]), fast_tanh(a[1]), fast_tanh(a[2]), fast_tanh(a[3]));
}
// relu applied on packed f16 (2x v_pk_max_f16): substitutes instructions,
// adds NO live state (r21 lesson: this body sits exactly at the reg cliff).
__device__ __forceinline__ f16x4 relu_pack(f32x4 a) {
#if __has_builtin(__builtin_elementwise_max)
    f16x4 v = pack4(a[0], a[1], a[2], a[3]);
    const f16x4 z = {(_Float16)0, (_Float16)0, (_Float16)0, (_Float16)0};
    return __builtin_elementwise_max(v, z);
#else
    return pack4(fmaxf(a[0], 0.f), fmaxf(a[1], 0.f), fmaxf(a[2], 0.f),
                 fmaxf(a[3], 0.f));
#endif
}
__device__ __forceinline__ f32x4 tanh4(f32x4 a) {
    return f32x4{fast_tanh(a[0]), fast_tanh(a[1]), fast_tanh(a[2]), fast_tanh(a[3])};
}

// ---- virtual-channel maps (verified r9-r19: absmax 0.0039) -----------------
__device__ __forceinline__ int col64(int k) {
    return 32 * (k >> 5) + 16 * ((k >> 2) & 1) + (((k >> 3) & 3) << 2) + (k & 3);
}
__device__ __forceinline__ int col32(int k) {
    return 16 * ((k >> 2) & 1) + ((k >> 3) << 2) + (k & 3);
}
__device__ __forceinline__ int col16(int k) {
    return (k & 3) | ((k >> 1) & 4) | ((k & 4) << 1);
}

// ---------------- prepacked weight storage (device globals) ----------------
// 17 MFMA steps (hi-only f16): B1:s0-3 (bias in k=31 col) B2:s4-7 B3:s8-9
// B4:s10  A2:s11-14 A3:s15 A4:s16. Main kernel uses s0-10; A-table builder
// uses s11-16. bias steps: B2:0-1 B3:2-3 B4:4 A2:5-6 A3:7 A4:8.
__device__ __align__(16) _Float16 g_frag[NP][17 * 64 * 8];
__device__ __align__(16) float    g_bias[NP][9 * 64 * 4];
__device__ __align__(16) float    g_a1w [NP][64 * 16];  // A1 in B-slot order
__device__ __align__(16) float    g_a1b [NP][64 * 16];
// fin: [0..15]=W56 (Wb6·Wb5), [16..31]=Wa5 zero-padded, [32]=b56, [33]=ba5
__device__ __align__(16) float    g_fin [NP][36];
// A-encoder tabulated: f_p at x = -6 + i*h, i = 0..4096
__device__ __align__(16) float    g_atab[NP][ATAB_N + 4];

// One block per (p, step) for the 17 frag steps + one per-p misc block.
__global__ void prep_frags(
    const float* __restrict__ Wa1, const float* __restrict__ ba1,
    const float* __restrict__ Wa2, const float* __restrict__ ba2,
    const float* __restrict__ Wa3, const float* __restrict__ ba3,
    const float* __restrict__ Wa4, const float* __restrict__ ba4,
    const float* __restrict__ Wa5, const float* __restrict__ ba5,
    const float* __restrict__ Wb1, const float* __restrict__ bb1,
    const float* __restrict__ Wb2, const float* __restrict__ bb2,
    const float* __restrict__ Wb3, const float* __restrict__ bb3,
    const float* __restrict__ Wb4, const float* __restrict__ bb4,
    const float* __restrict__ Wb5, const float* __restrict__ bb5,
    const float* __restrict__ Wb6, const float* __restrict__ bb6) {
    const int p    = blockIdx.x & 31;   // NP = 32
    const int task = blockIdx.x >> 5;   // 0..16 = frag step, 17 = misc
    const int l = threadIdx.x;          // 0..63
    const int g = l >> 4, q = l & 15;

    const int sw[17]  = {0,0,0,0, 1,1,1,1, 2,2, 3, 4,4,4,4, 5, 6};
    const int sMt[17] = {0,1,2,3, 0,0,1,1, 0,1, 0, 0,0,1,1, 0, 0};
    const int sks[17] = {0,0,0,0, 0,1,0,1, 0,0, 0, 0,1,0,1, 0, 0};
    const int OO[7] = {64,32,32,16,32,16, 8};
    const int II[7] = {31,64,32,32,64,32,16};
    const float* WS[7] = {Wb1 + p*1984, Wb2 + p*2048, Wb3 + p*1024,
                          Wb4 + p*512,  Wa2 + p*2048, Wa3 + p*512,
                          Wa4 + p*128};

    if (task < 17) {
        const int s = task;
        const int w = sw[s], O = OO[w], I = II[w];
        const float* W = WS[w];
        const float* b1s = bb1 + p*64;
#pragma unroll
        for (int e = 0; e < 8; ++e) {
            const int kk = 32*sks[s] + 8*g + e;   // layer-k slot
            const int o  = 16*sMt[s] + q;         // out (= A row)
            float wv = 0.0f;
            if (o < O) {
                if (s < 4) {        // B1: direct x order; col 31 = bias
                    wv = (kk < 31) ? W[o*31 + kk] : (kk == 31 ? b1s[o] : 0.0f);
                } else if (w == 1 || w == 4) {          // 64-wide input
                    wv = W[o*I + col64(kk)];
                } else if (w == 6) {                    // A4: 16-wide input
                    wv = (kk < 16) ? W[o*I + col16(kk)] : 0.0f;
                } else {                                // 32-wide input
                    wv = W[o*I + col32(kk)];
                }
            }
            g_frag[p][(s*64 + l)*8 + e] = (_Float16)wv;
        }
        return;
    }

    // ---- task 17: biases, A1 tables, fin ------------------------------------
    const int bw[9]  = {0,0, 1,1, 2, 3,3, 4, 5};
    const int bMt[9] = {0,1, 0,1, 0, 0,1, 0, 0};
    const float* BS[6] = {bb2 + p*32, bb3 + p*32, bb4 + p*16,
                          ba2 + p*32, ba3 + p*16, ba4 + p*8};
    const int BO[6] = {32,32,16,32,16,8};
#pragma unroll
    for (int bs = 0; bs < 9; ++bs) {
        const int w = bw[bs];
#pragma unroll
        for (int j = 0; j < 4; ++j) {
            const int o = 16*bMt[bs] + 4*g + j;
            g_bias[p][(bs*64 + l)*4 + j] = (o < BO[w]) ? BS[w][o] : 0.0f;
        }
    }
    // A1 weights directly in B-slot order (out channel = col64 of slot)
#pragma unroll
    for (int idx = 0; idx < 16; ++idx) {
        const int ks = idx >> 3, e = idx & 7;
        const int c = col64(32*ks + 8*g + e);
        g_a1w[p][l*16 + idx] = Wa1[p*64 + c];
        g_a1b[p][l*16 + idx] = ba1[p*64 + c];
    }
    // fin: W56 fold in parallel over 16 lanes, rest on lane 0
    if (l < 16) {
        float s = 0.0f;
        for (int o = 0; o < 8; ++o)
            s += Wb6[p*8 + o] * Wb5[p*128 + o*16 + l];
        g_fin[p][l] = s;
        g_fin[p][16 + l] = (l < 8) ? Wa5[p*8 + l] : 0.0f;
    }
    if (l == 0) {
        float s = bb6[p];
        for (int o = 0; o < 8; ++o) s += Wb6[p*8 + o] * bb5[p*8 + o];
        g_fin[p][32] = s;
        g_fin[p][33] = ba5[p];
    }
}

// ---------------- A-encoder table builder (unchanged from r16) --------------
#define ALOADN(s) nw = *(const f16x8*)(wla + ((s)*64 + l)*8);
#define AROT() cw = nw;
#define AMFMA(bop, acc) \
    acc = __builtin_amdgcn_mfma_f32_16x16x32_f16(cw, bop, acc, 0, 0, 0);

__global__ __launch_bounds__(256, 3) void build_atab(int dummy) {
    __shared__ __align__(16) _Float16 wla[6 * 64 * 8];   // steps 11..16, 6144 B
    const int p  = blockIdx.x / 17;
    const int rb = blockIdx.x % 17;
    const int wv = threadIdx.x >> 6;
    const int l  = threadIdx.x & 63;
    const int g  = l >> 4, q = l & 15;
    const int row0 = rb * 256 + wv * 64;

    {   // stage A-steps (bytes [11*1024, 17*1024) of g_frag[p])
        const uint4* src = (const uint4*)(&g_frag[p][11 * 512]);
        uint4* dst = (uint4*)wla;
        for (int i = threadIdx.x; i < 6144 / 16; i += 256) dst[i] = src[i];
    }
    const float* bias = g_bias[p];
    const float* fin  = g_fin[p];
    const f32x4 finA = *(const f32x4*)(fin + 16 + 4*g);
    const float ba5v = fin[33];
    const f32x4* a1wp = (const f32x4*)(g_a1w[p] + l*16);
    const f32x4* a1bp = (const f32x4*)(g_a1b[p] + l*16);
    f32x4 a1w[4], a1b[4];
#pragma unroll
    for (int i = 0; i < 4; ++i) { a1w[i] = a1wp[i]; a1b[i] = a1bp[i]; }

    float xa[4];
#pragma unroll
    for (int t = 0; t < 4; ++t)
        xa[t] = fmaf((float)(row0 + 16*t + q), ATAB_H, -6.0f);

    __syncthreads();

    f16x8 cw, nw;
    ALOADN(0);

    // A1: 1->64 relu on VALU
    f16x8 bA[4][2];
#pragma unroll
    for (int ks = 0; ks < 2; ++ks) {
#pragma unroll
        for (int t = 0; t < 4; ++t) {
            float c0[4], c1[4];
#pragma unroll
            for (int j = 0; j < 4; ++j) {
                c0[j] = fmaxf(fmaf(a1w[2*ks][j],   xa[t], a1b[2*ks][j]),   0.f);
                c1[j] = fmaxf(fmaf(a1w[2*ks+1][j], xa[t], a1b[2*ks+1][j]), 0.f);
            }
            bA[t][ks] = cat8(pack4(c0[0], c0[1], c0[2], c0[3]),
                             pack4(c1[0], c1[1], c1[2], c1[3]));
        }
    }

    // A2: 64->32 tanh (local steps 0-3, bias 5-6)
    f16x4 u[4][2];
#pragma unroll
    for (int Mt = 0; Mt < 2; ++Mt) {
        const f32x4 cb = *(const f32x4*)(bias + ((5 + Mt)*64 + l)*4);
        f32x4 a[4] = {cb, cb, cb, cb};
        AROT();
        ALOADN(1 + 2*Mt);
#pragma unroll
        for (int t = 0; t < 4; ++t) { AMFMA(bA[t][0], a[t]); }
        AROT();
        ALOADN(2 + 2*Mt);
#pragma unroll
        for (int t = 0; t < 4; ++t) { AMFMA(bA[t][1], a[t]); }
#pragma unroll
        for (int t = 0; t < 4; ++t) u[t][Mt] = tanh_pack(a[t]);
    }
    f16x8 a2[4];
#pragma unroll
    for (int t = 0; t < 4; ++t) a2[t] = cat8(u[t][0], u[t][1]);

    // A3: 32->16 tanh (local step 4, bias 7), halves swapped via xor32
    f16x8 a3f[4];
    {
        const f32x4 cb = *(const f32x4*)(bias + (7*64 + l)*4);
        AROT();
        ALOADN(5);
#pragma unroll
        for (int t = 0; t < 4; ++t) {
            f32x4 a = cb;
            AMFMA(a2[t], a);
            const f16x4 own = tanh_pack(a);
            const float2 ow = __builtin_bit_cast(float2, own);
            float2 pw;
            pw.x = __shfl_xor(ow.x, 32);
            pw.y = __shfl_xor(ow.y, 32);
            a3f[t] = cat8(own, __builtin_bit_cast(f16x4, pw));
        }
    }

    // A4: 16->8 tanh (local step 5, bias 8) + A5 dot + table store
    {
        const f32x4 cb = *(const f32x4*)(bias + (8*64 + l)*4);
        AROT();
#pragma unroll
        for (int t = 0; t < 4; ++t) {
            f32x4 a = cb;
            AMFMA(a3f[t], a);
            const f32x4 c = tanh4(a);
            float s = finA[0] * c[0];
            s = fmaf(finA[1], c[1], s);
            s = fmaf(finA[2], c[2], s);
            s = fmaf(finA[3], c[3], s);
            s += __shfl_xor(s, 16);
            s += __shfl_xor(s, 32);
            const int row = row0 + 16*t + q;
            if (g == 0 && row <= ATAB_N) g_atab[p][row] = s + ba5v;
        }
    }
}

// ---------------- main kernel: exact r19 body (+pk relu only) ---------------
// (256,4) is the occupancy ceiling: unified-file acc block (~44) + arch 64
// fits the 128 budget; 5/6-wave tiers leave <64 arch -> spill (r14/r20).
// r21 lesson: adding ANY persistent live values (B1 f32 bias init) tips the
// RA over the cliff -> 380 MB scratch. Keep B1 bias in the k=31 weight col.
#define LOADW(s) w = *(const f16x8*)(wlds + ((s)*64 + l)*8);
#define MFMAW(bop, acc) \
    acc = __builtin_amdgcn_mfma_f32_16x16x32_f16(w, bop, acc, 0, 0, 0);
#define BIAS4(bs) (*(const f32x4*)(bias + ((bs)*64 + l)*4))

__global__ __launch_bounds__(256, 4) void mlp_mfma(
    const float* __restrict__ x, float* __restrict__ out) {
    __shared__ __align__(16) _Float16 wlds[11 * 64 * 8];  // 11264 B

    const int L   = blockIdx.x;          // 0..4095
    const int xcd = L & 7;
    const int m   = L >> 3;
    const int p   = m & 31;              // feature
    const int rc  = xcd + 8 * (m >> 5);  // row chunk 0..127
    const int wv  = threadIdx.x >> 6;
    const int l   = threadIdx.x & 63;
    const int g   = l >> 4, q = l & 15;
    const int wrow = rc * 512 + wv * 128;   // 128 rows per wave

    {   // stage B-steps (11264 B) once per block
        const uint4* src = (const uint4*)(g_frag[p]);
        uint4* dst = (uint4*)wlds;
        for (int i = threadIdx.x; i < 11264 / 16; i += 256) dst[i] = src[i];
    }

    const float* bias = g_bias[p];
    const float* fin  = g_fin[p];
    const f32x4 finB = *(const f32x4*)(fin + 4*g);
    const float b56 = fin[32];

    __syncthreads();

#pragma unroll 1
    for (int hg = 0; hg < 2; ++hg) {
        const int row0 = wrow + hg * 64;

        // ---- x operands (vectorized) + A-table lerp -------------------------
        f16x8 bX[4];
        float av[4];
#pragma unroll
        for (int t = 0; t < 4; ++t) {
            const float* xr = x + (size_t)(row0 + 16*t + q) * NP;
            const f32x4 v0 = *(const f32x4*)(xr + 8*g);
            const f32x4 v1 = *(const f32x4*)(xr + 8*g + 4);
            const float ex = xr[(8*g + 8 < 32) ? (8*g + 8) : 31];
            float r[9] = {v0[0], v0[1], v0[2], v0[3],
                          v1[0], v1[1], v1[2], v1[3], ex};
            float c[8];
#pragma unroll
            for (int e = 0; e < 8; ++e) {
                const int k = 8*g + e;
                c[e] = (k < 31) ? ((k >= p) ? r[e + 1] : r[e]) : 1.0f;
            }
            bX[t] = cat8(pack4(c[0], c[1], c[2], c[3]),
                         pack4(c[4], c[5], c[6], c[7]));
            const float xa = xr[p];
            float u = (xa + 6.0f) * ATAB_SCALE;
            u = fminf(fmaxf(u, 0.0f), 4095.99f);
            const int i = (int)u;
            const float fr = u - (float)i;
            const float t0 = g_atab[p][i];
            const float t1 = g_atab[p][i + 1];
            av[t] = fmaf(fr, t1 - t0, t0);
        }

        f16x8 w;

        // ---- B1: 31->64 relu (bias folded in k=31 column), steps 0-3 -------
        f16x4 h[4][4];
#pragma unroll
        for (int Mt = 0; Mt < 4; ++Mt) {
            LOADW(Mt);
#pragma unroll
            for (int t = 0; t < 4; ++t) {
                f32x4 a{0.f, 0.f, 0.f, 0.f};
                MFMAW(bX[t], a);
                h[t][Mt] = relu_pack(a);
            }
        }
        f16x8 bk[4][2];
#pragma unroll
        for (int t = 0; t < 4; ++t) {
            bk[t][0] = cat8(h[t][0], h[t][1]);
            bk[t][1] = cat8(h[t][2], h[t][3]);
        }

        // ---- B2: 64->32 tanh (steps 4-7, bias 0-1) -------------------------
        f16x4 u[4][2];
#pragma unroll
        for (int Mt = 0; Mt < 2; ++Mt) {
            const f32x4 cb = BIAS4(0 + Mt);
            f16x8 w0 = *(const f16x8*)(wlds + ((4 + 2*Mt)*64 + l)*8);
            f16x8 w1 = *(const f16x8*)(wlds + ((5 + 2*Mt)*64 + l)*8);
#pragma unroll
            for (int t = 0; t < 4; ++t) {
                f32x4 a = cb;
                a = __builtin_amdgcn_mfma_f32_16x16x32_f16(w0, bk[t][0], a, 0, 0, 0);
                a = __builtin_amdgcn_mfma_f32_16x16x32_f16(w1, bk[t][1], a, 0, 0, 0);
                u[t][Mt] = tanh_pack(a);
            }
        }
        f16x8 b2[4];
#pragma unroll
        for (int t = 0; t < 4; ++t) b2[t] = cat8(u[t][0], u[t][1]);

        // ---- B3: 32->32 tanh (steps 8-9, bias 2-3) -------------------------
#pragma unroll
        for (int Mt = 0; Mt < 2; ++Mt) {
            const f32x4 cb = BIAS4(2 + Mt);
            LOADW(8 + Mt);
#pragma unroll
            for (int t = 0; t < 4; ++t) {
                f32x4 a = cb;
                MFMAW(b2[t], a);
                u[t][Mt] = tanh_pack(a);
            }
        }
        f16x8 b3[4];
#pragma unroll
        for (int t = 0; t < 4; ++t) b3[t] = cat8(u[t][0], u[t][1]);

        // ---- B4: 32->16 tanh (step 10, bias 4) + folded B5·B6 dot + store --
        {
            const f32x4 cb = BIAS4(4);
            LOADW(10);
#pragma unroll
            for (int t = 0; t < 4; ++t) {
                f32x4 a = cb;
                MFMAW(b3[t], a);
                const f32x4 c = tanh4(a);
                float s = finB[0] * c[0];
                s = fmaf(finB[1], c[1], s);
                s = fmaf(finB[2], c[2], s);
                s = fmaf(finB[3], c[3], s);
                s += __shfl_xor(s, 16);
                s += __shfl_xor(s, 32);
                const float bv = s + b56;
                if (g == 0) {
                    const int grow = row0 + 16*t + q;
                    reinterpret_cast<float2*>(out)[(size_t)grow * NP + p] =
                        make_float2(av[t], bv);
                }
            }
        }
    }
}

extern "C" void kernel_launch(void* const* d_in, const int* in_sizes, int n_in,
                              void* d_out, int out_size, void* d_ws,
                              size_t ws_size, hipStream_t stream) {
    const float* x   = (const float*)d_in[0];
    const float* Wa1 = (const float*)d_in[1];
    const float* ba1 = (const float*)d_in[2];
    const float* Wa2 = (const float*)d_in[3];
    const float* ba2 = (const float*)d_in[4];
    const float* Wa3 = (const float*)d_in[5];
    const float* ba3 = (const float*)d_in[6];
    const float* Wa4 = (const float*)d_in[7];
    const float* ba4 = (const float*)d_in[8];
    const float* Wa5 = (const float*)d_in[9];
    const float* ba5 = (const float*)d_in[10];
    const float* Wb1 = (const float*)d_in[11];
    const float* bb1 = (const float*)d_in[12];
    const float* Wb2 = (const float*)d_in[13];
    const float* bb2 = (const float*)d_in[14];
    const float* Wb3 = (const float*)d_in[15];
    const float* bb3 = (const float*)d_in[16];
    const float* Wb4 = (const float*)d_in[17];
    const float* bb4 = (const float*)d_in[18];
    const float* Wb5 = (const float*)d_in[19];
    const float* bb5 = (const float*)d_in[20];
    const float* Wb6 = (const float*)d_in[21];
    const float* bb6 = (const float*)d_in[22];

    prep_frags<<<dim3(NP * 18), dim3(64), 0, stream>>>(
        Wa1, ba1, Wa2, ba2, Wa3, ba3, Wa4, ba4, Wa5, ba5,
        Wb1, bb1, Wb2, bb2, Wb3, bb3, Wb4, bb4, Wb5, bb5, Wb6, bb6);

    build_atab<<<dim3(NP * 17), dim3(256), 0, stream>>>(0);

    mlp_mfma<<<dim3(NROWS / 512 * NP), 256, 0, stream>>>(x, (float*)d_out);
}

// Round 23
// 105.041 us; speedup vs baseline: 2.2314x; 1.1750x over previous
//
#include <hip/hip_runtime.h>

#define NP 32
#define NROWS 65536
#define ATAB_N 4096               // intervals over [-6, 6]; h = 3/1024 exact
#define ATAB_H (3.0f / 1024.0f)
#define ATAB_SCALE (4096.0f / 12.0f)

typedef _Float16 f16x8 __attribute__((ext_vector_type(8)));
typedef _Float16 f16x4 __attribute__((ext_vector_type(4)));
typedef _Float16 f16x2 __attribute__((ext_vector_type(2)));
typedef float    f32x4 __attribute__((ext_vector_type(4)));

#define FAST_RCP(x) __builtin_amdgcn_rcpf(x)

__device__ __forceinline__ float fast_tanh(float v) {
    float e = __expf(2.0f * v);
    return fmaf(-2.0f, FAST_RCP(e + 1.0f), 1.0f);
}

__device__ __forceinline__ f16x4 pack4(float c0, float c1, float c2, float c3) {
    const f16x2 p01 = __builtin_bit_cast(f16x2, __builtin_amdgcn_cvt_pkrtz(c0, c1));
    const f16x2 p23 = __builtin_bit_cast(f16x2, __builtin_amdgcn_cvt_pkrtz(c2, c3));
    return __builtin_shufflevector(p01, p23, 0, 1, 2, 3);
}
__device__ __forceinline__ f16x8 cat8(f16x4 a, f16x4 b) {
    return __builtin_shufflevector(a, b, 0, 1, 2, 3, 4, 5, 6, 7);
}
__device__ __forceinline__ f16x4 tanh_pack(f32x4 a) {
    return pack4(fast_tanh(a[0]), fast_tanh(a[1]), fast_tanh(a[2]), fast_tanh(a[3]));
}
// f32-side relu (r22 lesson: even substituting pk_max_f16 after the pack
// re-ordered lifetimes enough to tip the RA into a mild spill; keep r19 form).
__device__ __forceinline__ f16x4 relu_pack(f32x4 a) {
    return pack4(fmaxf(a[0], 0.f), fmaxf(a[1], 0.f), fmaxf(a[2], 0.f),
                 fmaxf(a[3], 0.f));
}
__device__ __forceinline__ f32x4 tanh4(f32x4 a) {
    return f32x4{fast_tanh(a[0]), fast_tanh(a[1]), fast_tanh(a[2]), fast_tanh(a[3])};
}

// ---- virtual-channel maps (verified r9-r19: absmax 0.0039) -----------------
__device__ __forceinline__ int col64(int k) {
    return 32 * (k >> 5) + 16 * ((k >> 2) & 1) + (((k >> 3) & 3) << 2) + (k & 3);
}
__device__ __forceinline__ int col32(int k) {
    return 16 * ((k >> 2) & 1) + ((k >> 3) << 2) + (k & 3);
}
__device__ __forceinline__ int col16(int k) {
    return (k & 3) | ((k >> 1) & 4) | ((k & 4) << 1);
}

// ---------------- prepacked weight storage (device globals) ----------------
// 17 MFMA steps (hi-only f16): B1:s0-3 (bias in k=31 col) B2:s4-7 B3:s8-9
// B4:s10  A2:s11-14 A3:s15 A4:s16. Main kernel uses s0-10; A-table builder
// uses s11-16. bias steps: B2:0-1 B3:2-3 B4:4 A2:5-6 A3:7 A4:8.
__device__ __align__(16) _Float16 g_frag[NP][17 * 64 * 8];
__device__ __align__(16) float    g_bias[NP][9 * 64 * 4];
__device__ __align__(16) float    g_a1w [NP][64 * 16];  // A1 in B-slot order
__device__ __align__(16) float    g_a1b [NP][64 * 16];
// fin: [0..15]=W56 (Wb6·Wb5), [16..31]=Wa5 zero-padded, [32]=b56, [33]=ba5
__device__ __align__(16) float    g_fin [NP][36];
// A-encoder tabulated: f_p at x = -6 + i*h, i = 0..4096
__device__ __align__(16) float    g_atab[NP][ATAB_N + 4];

// One block per (p, step) for the 17 frag steps + one per-p misc block.
__global__ void prep_frags(
    const float* __restrict__ Wa1, const float* __restrict__ ba1,
    const float* __restrict__ Wa2, const float* __restrict__ ba2,
    const float* __restrict__ Wa3, const float* __restrict__ ba3,
    const float* __restrict__ Wa4, const float* __restrict__ ba4,
    const float* __restrict__ Wa5, const float* __restrict__ ba5,
    const float* __restrict__ Wb1, const float* __restrict__ bb1,
    const float* __restrict__ Wb2, const float* __restrict__ bb2,
    const float* __restrict__ Wb3, const float* __restrict__ bb3,
    const float* __restrict__ Wb4, const float* __restrict__ bb4,
    const float* __restrict__ Wb5, const float* __restrict__ bb5,
    const float* __restrict__ Wb6, const float* __restrict__ bb6) {
    const int p    = blockIdx.x & 31;   // NP = 32
    const int task = blockIdx.x >> 5;   // 0..16 = frag step, 17 = misc
    const int l = threadIdx.x;          // 0..63
    const int g = l >> 4, q = l & 15;

    const int sw[17]  = {0,0,0,0, 1,1,1,1, 2,2, 3, 4,4,4,4, 5, 6};
    const int sMt[17] = {0,1,2,3, 0,0,1,1, 0,1, 0, 0,0,1,1, 0, 0};
    const int sks[17] = {0,0,0,0, 0,1,0,1, 0,0, 0, 0,1,0,1, 0, 0};
    const int OO[7] = {64,32,32,16,32,16, 8};
    const int II[7] = {31,64,32,32,64,32,16};
    const float* WS[7] = {Wb1 + p*1984, Wb2 + p*2048, Wb3 + p*1024,
                          Wb4 + p*512,  Wa2 + p*2048, Wa3 + p*512,
                          Wa4 + p*128};

    if (task < 17) {
        const int s = task;
        const int w = sw[s], O = OO[w], I = II[w];
        const float* W = WS[w];
        const float* b1s = bb1 + p*64;
#pragma unroll
        for (int e = 0; e < 8; ++e) {
            const int kk = 32*sks[s] + 8*g + e;   // layer-k slot
            const int o  = 16*sMt[s] + q;         // out (= A row)
            float wv = 0.0f;
            if (o < O) {
                if (s < 4) {        // B1: direct x order; col 31 = bias
                    wv = (kk < 31) ? W[o*31 + kk] : (kk == 31 ? b1s[o] : 0.0f);
                } else if (w == 1 || w == 4) {          // 64-wide input
                    wv = W[o*I + col64(kk)];
                } else if (w == 6) {                    // A4: 16-wide input
                    wv = (kk < 16) ? W[o*I + col16(kk)] : 0.0f;
                } else {                                // 32-wide input
                    wv = W[o*I + col32(kk)];
                }
            }
            g_frag[p][(s*64 + l)*8 + e] = (_Float16)wv;
        }
        return;
    }

    // ---- task 17: biases, A1 tables, fin ------------------------------------
    const int bw[9]  = {0,0, 1,1, 2, 3,3, 4, 5};
    const int bMt[9] = {0,1, 0,1, 0, 0,1, 0, 0};
    const float* BS[6] = {bb2 + p*32, bb3 + p*32, bb4 + p*16,
                          ba2 + p*32, ba3 + p*16, ba4 + p*8};
    const int BO[6] = {32,32,16,32,16,8};
#pragma unroll
    for (int bs = 0; bs < 9; ++bs) {
        const int w = bw[bs];
#pragma unroll
        for (int j = 0; j < 4; ++j) {
            const int o = 16*bMt[bs] + 4*g + j;
            g_bias[p][(bs*64 + l)*4 + j] = (o < BO[w]) ? BS[w][o] : 0.0f;
        }
    }
    // A1 weights directly in B-slot order (out channel = col64 of slot)
#pragma unroll
    for (int idx = 0; idx < 16; ++idx) {
        const int ks = idx >> 3, e = idx & 7;
        const int c = col64(32*ks + 8*g + e);
        g_a1w[p][l*16 + idx] = Wa1[p*64 + c];
        g_a1b[p][l*16 + idx] = ba1[p*64 + c];
    }
    // fin: W56 fold in parallel over 16 lanes, rest on lane 0
    if (l < 16) {
        float s = 0.0f;
        for (int o = 0; o < 8; ++o)
            s += Wb6[p*8 + o] * Wb5[p*128 + o*16 + l];
        g_fin[p][l] = s;
        g_fin[p][16 + l] = (l < 8) ? Wa5[p*8 + l] : 0.0f;
    }
    if (l == 0) {
        float s = bb6[p];
        for (int o = 0; o < 8; ++o) s += Wb6[p*8 + o] * bb5[p*8 + o];
        g_fin[p][32] = s;
        g_fin[p][33] = ba5[p];
    }
}

// ---------------- A-encoder table builder (unchanged from r16) --------------
#define ALOADN(s) nw = *(const f16x8*)(wla + ((s)*64 + l)*8);
#define AROT() cw = nw;
#define AMFMA(bop, acc) \
    acc = __builtin_amdgcn_mfma_f32_16x16x32_f16(cw, bop, acc, 0, 0, 0);

__global__ __launch_bounds__(256, 3) void build_atab(int dummy) {
    __shared__ __align__(16) _Float16 wla[6 * 64 * 8];   // steps 11..16, 6144 B
    const int p  = blockIdx.x / 17;
    const int rb = blockIdx.x % 17;
    const int wv = threadIdx.x >> 6;
    const int l  = threadIdx.x & 63;
    const int g  = l >> 4, q = l & 15;
    const int row0 = rb * 256 + wv * 64;

    {   // stage A-steps (bytes [11*1024, 17*1024) of g_frag[p])
        const uint4* src = (const uint4*)(&g_frag[p][11 * 512]);
        uint4* dst = (uint4*)wla;
        for (int i = threadIdx.x; i < 6144 / 16; i += 256) dst[i] = src[i];
    }
    const float* bias = g_bias[p];
    const float* fin  = g_fin[p];
    const f32x4 finA = *(const f32x4*)(fin + 16 + 4*g);
    const float ba5v = fin[33];
    const f32x4* a1wp = (const f32x4*)(g_a1w[p] + l*16);
    const f32x4* a1bp = (const f32x4*)(g_a1b[p] + l*16);
    f32x4 a1w[4], a1b[4];
#pragma unroll
    for (int i = 0; i < 4; ++i) { a1w[i] = a1wp[i]; a1b[i] = a1bp[i]; }

    float xa[4];
#pragma unroll
    for (int t = 0; t < 4; ++t)
        xa[t] = fmaf((float)(row0 + 16*t + q), ATAB_H, -6.0f);

    __syncthreads();

    f16x8 cw, nw;
    ALOADN(0);

    // A1: 1->64 relu on VALU
    f16x8 bA[4][2];
#pragma unroll
    for (int ks = 0; ks < 2; ++ks) {
#pragma unroll
        for (int t = 0; t < 4; ++t) {
            float c0[4], c1[4];
#pragma unroll
            for (int j = 0; j < 4; ++j) {
                c0[j] = fmaxf(fmaf(a1w[2*ks][j],   xa[t], a1b[2*ks][j]),   0.f);
                c1[j] = fmaxf(fmaf(a1w[2*ks+1][j], xa[t], a1b[2*ks+1][j]), 0.f);
            }
            bA[t][ks] = cat8(pack4(c0[0], c0[1], c0[2], c0[3]),
                             pack4(c1[0], c1[1], c1[2], c1[3]));
        }
    }

    // A2: 64->32 tanh (local steps 0-3, bias 5-6)
    f16x4 u[4][2];
#pragma unroll
    for (int Mt = 0; Mt < 2; ++Mt) {
        const f32x4 cb = *(const f32x4*)(bias + ((5 + Mt)*64 + l)*4);
        f32x4 a[4] = {cb, cb, cb, cb};
        AROT();
        ALOADN(1 + 2*Mt);
#pragma unroll
        for (int t = 0; t < 4; ++t) { AMFMA(bA[t][0], a[t]); }
        AROT();
        ALOADN(2 + 2*Mt);
#pragma unroll
        for (int t = 0; t < 4; ++t) { AMFMA(bA[t][1], a[t]); }
#pragma unroll
        for (int t = 0; t < 4; ++t) u[t][Mt] = tanh_pack(a[t]);
    }
    f16x8 a2[4];
#pragma unroll
    for (int t = 0; t < 4; ++t) a2[t] = cat8(u[t][0], u[t][1]);

    // A3: 32->16 tanh (local step 4, bias 7), halves swapped via xor32
    f16x8 a3f[4];
    {
        const f32x4 cb = *(const f32x4*)(bias + (7*64 + l)*4);
        AROT();
        ALOADN(5);
#pragma unroll
        for (int t = 0; t < 4; ++t) {
            f32x4 a = cb;
            AMFMA(a2[t], a);
            const f16x4 own = tanh_pack(a);
            const float2 ow = __builtin_bit_cast(float2, own);
            float2 pw;
            pw.x = __shfl_xor(ow.x, 32);
            pw.y = __shfl_xor(ow.y, 32);
            a3f[t] = cat8(own, __builtin_bit_cast(f16x4, pw));
        }
    }

    // A4: 16->8 tanh (local step 5, bias 8) + A5 dot + table store
    {
        const f32x4 cb = *(const f32x4*)(bias + (8*64 + l)*4);
        AROT();
#pragma unroll
        for (int t = 0; t < 4; ++t) {
            f32x4 a = cb;
            AMFMA(a3f[t], a);
            const f32x4 c = tanh4(a);
            float s = finA[0] * c[0];
            s = fmaf(finA[1], c[1], s);
            s = fmaf(finA[2], c[2], s);
            s = fmaf(finA[3], c[3], s);
            s += __shfl_xor(s, 16);
            s += __shfl_xor(s, 32);
            const int row = row0 + 16*t + q;
            if (g == 0 && row <= ATAB_N) g_atab[p][row] = s + ba5v;
        }
    }
}

// ---------------- main kernel: exact r19 body (105us bench, 98us dispatch) --
// (256,4) is the occupancy ceiling: unified-file acc block (~44) + arch 64
// fits the 128 budget; 5/6-wave tiers leave <64 arch -> spill (r14/r20).
// r21/r22 lessons: ANY added live state or even instruction substitution
// near the cliff (pk relu) flips the RA into spilling. Do not perturb.
#define LOADW(s) w = *(const f16x8*)(wlds + ((s)*64 + l)*8);
#define MFMAW(bop, acc) \
    acc = __builtin_amdgcn_mfma_f32_16x16x32_f16(w, bop, acc, 0, 0, 0);
#define BIAS4(bs) (*(const f32x4*)(bias + ((bs)*64 + l)*4))

__global__ __launch_bounds__(256, 4) void mlp_mfma(
    const float* __restrict__ x, float* __restrict__ out) {
    __shared__ __align__(16) _Float16 wlds[11 * 64 * 8];  // 11264 B

    const int L   = blockIdx.x;          // 0..4095
    const int xcd = L & 7;
    const int m   = L >> 3;
    const int p   = m & 31;              // feature
    const int rc  = xcd + 8 * (m >> 5);  // row chunk 0..127
    const int wv  = threadIdx.x >> 6;
    const int l   = threadIdx.x & 63;
    const int g   = l >> 4, q = l & 15;
    const int wrow = rc * 512 + wv * 128;   // 128 rows per wave

    {   // stage B-steps (11264 B) once per block
        const uint4* src = (const uint4*)(g_frag[p]);
        uint4* dst = (uint4*)wlds;
        for (int i = threadIdx.x; i < 11264 / 16; i += 256) dst[i] = src[i];
    }

    const float* bias = g_bias[p];
    const float* fin  = g_fin[p];
    const f32x4 finB = *(const f32x4*)(fin + 4*g);
    const float b56 = fin[32];

    __syncthreads();

#pragma unroll 1
    for (int hg = 0; hg < 2; ++hg) {
        const int row0 = wrow + hg * 64;

        // ---- x operands (vectorized) + A-table lerp -------------------------
        f16x8 bX[4];
        float av[4];
#pragma unroll
        for (int t = 0; t < 4; ++t) {
            const float* xr = x + (size_t)(row0 + 16*t + q) * NP;
            const f32x4 v0 = *(const f32x4*)(xr + 8*g);
            const f32x4 v1 = *(const f32x4*)(xr + 8*g + 4);
            const float ex = xr[(8*g + 8 < 32) ? (8*g + 8) : 31];
            float r[9] = {v0[0], v0[1], v0[2], v0[3],
                          v1[0], v1[1], v1[2], v1[3], ex};
            float c[8];
#pragma unroll
            for (int e = 0; e < 8; ++e) {
                const int k = 8*g + e;
                c[e] = (k < 31) ? ((k >= p) ? r[e + 1] : r[e]) : 1.0f;
            }
            bX[t] = cat8(pack4(c[0], c[1], c[2], c[3]),
                         pack4(c[4], c[5], c[6], c[7]));
            const float xa = xr[p];
            float u = (xa + 6.0f) * ATAB_SCALE;
            u = fminf(fmaxf(u, 0.0f), 4095.99f);
            const int i = (int)u;
            const float fr = u - (float)i;
            const float t0 = g_atab[p][i];
            const float t1 = g_atab[p][i + 1];
            av[t] = fmaf(fr, t1 - t0, t0);
        }

        f16x8 w;

        // ---- B1: 31->64 relu (bias folded in k=31 column), steps 0-3 -------
        f16x4 h[4][4];
#pragma unroll
        for (int Mt = 0; Mt < 4; ++Mt) {
            LOADW(Mt);
#pragma unroll
            for (int t = 0; t < 4; ++t) {
                f32x4 a{0.f, 0.f, 0.f, 0.f};
                MFMAW(bX[t], a);
                h[t][Mt] = relu_pack(a);
            }
        }
        f16x8 bk[4][2];
#pragma unroll
        for (int t = 0; t < 4; ++t) {
            bk[t][0] = cat8(h[t][0], h[t][1]);
            bk[t][1] = cat8(h[t][2], h[t][3]);
        }

        // ---- B2: 64->32 tanh (steps 4-7, bias 0-1) -------------------------
        f16x4 u[4][2];
#pragma unroll
        for (int Mt = 0; Mt < 2; ++Mt) {
            const f32x4 cb = BIAS4(0 + Mt);
            f16x8 w0 = *(const f16x8*)(wlds + ((4 + 2*Mt)*64 + l)*8);
            f16x8 w1 = *(const f16x8*)(wlds + ((5 + 2*Mt)*64 + l)*8);
#pragma unroll
            for (int t = 0; t < 4; ++t) {
                f32x4 a = cb;
                a = __builtin_amdgcn_mfma_f32_16x16x32_f16(w0, bk[t][0], a, 0, 0, 0);
                a = __builtin_amdgcn_mfma_f32_16x16x32_f16(w1, bk[t][1], a, 0, 0, 0);
                u[t][Mt] = tanh_pack(a);
            }
        }
        f16x8 b2[4];
#pragma unroll
        for (int t = 0; t < 4; ++t) b2[t] = cat8(u[t][0], u[t][1]);

        // ---- B3: 32->32 tanh (steps 8-9, bias 2-3) -------------------------
#pragma unroll
        for (int Mt = 0; Mt < 2; ++Mt) {
            const f32x4 cb = BIAS4(2 + Mt);
            LOADW(8 + Mt);
#pragma unroll
            for (int t = 0; t < 4; ++t) {
                f32x4 a = cb;
                MFMAW(b2[t], a);
                u[t][Mt] = tanh_pack(a);
            }
        }
        f16x8 b3[4];
#pragma unroll
        for (int t = 0; t < 4; ++t) b3[t] = cat8(u[t][0], u[t][1]);

        // ---- B4: 32->16 tanh (step 10, bias 4) + folded B5·B6 dot + store --
        {
            const f32x4 cb = BIAS4(4);
            LOADW(10);
#pragma unroll
            for (int t = 0; t < 4; ++t) {
                f32x4 a = cb;
                MFMAW(b3[t], a);
                const f32x4 c = tanh4(a);
                float s = finB[0] * c[0];
                s = fmaf(finB[1], c[1], s);
                s = fmaf(finB[2], c[2], s);
                s = fmaf(finB[3], c[3], s);
                s += __shfl_xor(s, 16);
                s += __shfl_xor(s, 32);
                const float bv = s + b56;
                if (g == 0) {
                    const int grow = row0 + 16*t + q;
                    reinterpret_cast<float2*>(out)[(size_t)grow * NP + p] =
                        make_float2(av[t], bv);
                }
            }
        }
    }
}

extern "C" void kernel_launch(void* const* d_in, const int* in_sizes, int n_in,
                              void* d_out, int out_size, void* d_ws,
                              size_t ws_size, hipStream_t stream) {
    const float* x   = (const float*)d_in[0];
    const float* Wa1 = (const float*)d_in[1];
    const float* ba1 = (const float*)d_in[2];
    const float* Wa2 = (const float*)d_in[3];
    const float* ba2 = (const float*)d_in[4];
    const float* Wa3 = (const float*)d_in[5];
    const float* ba3 = (const float*)d_in[6];
    const float* Wa4 = (const float*)d_in[7];
    const float* ba4 = (const float*)d_in[8];
    const float* Wa5 = (const float*)d_in[9];
    const float* ba5 = (const float*)d_in[10];
    const float* Wb1 = (const float*)d_in[11];
    const float* bb1 = (const float*)d_in[12];
    const float* Wb2 = (const float*)d_in[13];
    const float* bb2 = (const float*)d_in[14];
    const float* Wb3 = (const float*)d_in[15];
    const float* bb3 = (const float*)d_in[16];
    const float* Wb4 = (const float*)d_in[17];
    const float* bb4 = (const float*)d_in[18];
    const float* Wb5 = (const float*)d_in[19];
    const float* bb5 = (const float*)d_in[20];
    const float* Wb6 = (const float*)d_in[21];
    const float* bb6 = (const float*)d_in[22];

    prep_frags<<<dim3(NP * 18), dim3(64), 0, stream>>>(
        Wa1, ba1, Wa2, ba2, Wa3, ba3, Wa4, ba4, Wa5, ba5,
        Wb1, bb1, Wb2, bb2, Wb3, bb3, Wb4, bb4, Wb5, bb5, Wb6, bb6);

    build_atab<<<dim3(NP * 17), dim3(256), 0, stream>>>(0);

    mlp_mfma<<<dim3(NROWS / 512 * NP), 256, 0, stream>>>(x, (float*)d_out);
}